// Round 1
// baseline (477.759 us; speedup 1.0000x reference)
//
#include <hip/hip_runtime.h>
#include <hip/hip_bf16.h>

#define B_ 64
#define L_ 128
#define P_ 64
#define E_ 128
#define H_ 128
#define M_ 32      // rows per block
#define NT_ 512    // 8 waves

typedef __attribute__((ext_vector_type(8))) short bf16x8;
typedef __attribute__((ext_vector_type(4))) float f32x4;

__device__ __forceinline__ unsigned short f2bf(float f){
    unsigned u = __builtin_bit_cast(unsigned, f);
    u += 0x7fffu + ((u >> 16) & 1u);            // RNE
    return (unsigned short)(u >> 16);
}
__device__ __forceinline__ float bf2f(unsigned short h){
    return __builtin_bit_cast(float, ((unsigned)h) << 16);
}
__device__ __forceinline__ float tanh_fast(float x){
    float ax = fminf(fabsf(x), 20.0f);
    float e  = __expf(2.0f * ax);
    float r  = 1.0f - 2.0f * __builtin_amdgcn_rcpf(e + 1.0f);
    return copysignf(r, x);
}
// XOR-swizzled bf16 tile helpers: tile is [32 rows][128 cols] bf16, 256 B/row.
// byte ^= (row&7)<<4 spreads the 256B-stride columns across 8 bank groups.
__device__ __forceinline__ void st16(unsigned short* arr, int row, int col, unsigned short v){
    int byte = ((row << 8) + (col << 1)) ^ ((row & 7) << 4);
    *(unsigned short*)((char*)arr + byte) = v;
}
__device__ __forceinline__ bf16x8 ldfrag(const unsigned short* arr, int row, int kb){
    int byte = ((row << 8) + (kb << 1)) ^ ((row & 7) << 4);   // kb multiple of 8 -> 16B aligned
    return *(const bf16x8*)((const char*)arr + byte);
}
__device__ __forceinline__ f32x4 mfma16(bf16x8 a, bf16x8 b, f32x4 c){
    return __builtin_amdgcn_mfma_f32_16x16x32_bf16(a, b, c, 0, 0, 0);
}

template<bool ATOMIC>
__global__ __launch_bounds__(NT_) void wode_main(
    const float* __restrict__ x,   const float* __restrict__ his,
    const float* __restrict__ pre, const float* __restrict__ W1,
    const float* __restrict__ b1,  const float* __restrict__ W2,
    const float* __restrict__ b2,  float* __restrict__ dst)
{
    __shared__ __align__(16) unsigned short sA_hi[M_*E_], sA_lo[M_*E_];  // stage input (hi/lo bf16)
    __shared__ __align__(16) unsigned short sB_hi[M_*E_], sB_lo[M_*E_];  // tanh intermediate
    __shared__ float wLP[M_][P_];     // w[l,p] for this block's 32 l's (normalized)
    __shared__ float hisq[M_];
    __shared__ float dstep[P_];       // dt for steps p>=1 (uniform over l)
    __shared__ float den_s[P_];
    __shared__ float pred[2][E_];     // per-step row-half partial reduction

    const int tid  = threadIdx.x;
    const int lane = tid & 63;
    const int w    = tid >> 6;
    const int r15  = lane & 15;
    const int hi16 = lane >> 4;
    const int mh   = w & 1;           // row half: rows [16*mh, 16*mh+16)
    const int nq   = w >> 1;          // col slice: cols [32*nq, 32*nq+32)
    const int b    = blockIdx.x >> 2;
    const int qb   = blockIdx.x & 3;  // l-quarter: l = 32*qb + row

    // ---- weights -> hi/lo bf16 B-fragments in registers ----
    bf16x8 w1h[4][2], w1l[4][2], w2h[4][2], w2l[4][2];   // [kt][nt]
    #pragma unroll
    for (int kt = 0; kt < 4; ++kt)
    #pragma unroll
    for (int nt = 0; nt < 2; ++nt){
        const int c  = nq*32 + nt*16 + r15;
        const int kb = kt*32 + hi16*8;
        bf16x8 h1, l1, h2, l2;
        #pragma unroll
        for (int j = 0; j < 8; ++j){
            float v1 = W1[(kb + j)*H_ + c];
            unsigned short hh1 = f2bf(v1);
            h1[j] = (short)hh1; l1[j] = (short)f2bf(v1 - bf2f(hh1));
            float v2 = W2[(kb + j)*E_ + c];
            unsigned short hh2 = f2bf(v2);
            h2[j] = (short)hh2; l2[j] = (short)f2bf(v2 - bf2f(hh2));
        }
        w1h[kt][nt] = h1; w1l[kt][nt] = l1;
        w2h[kt][nt] = h2; w2l[kt][nt] = l2;
    }
    float b1v[2], b2v[2];
    #pragma unroll
    for (int nt = 0; nt < 2; ++nt){
        const int c = nq*32 + nt*16 + r15;
        b1v[nt] = b1[c]; b2v[nt] = b2[c];
    }

    // ---- z init (C-fragment layout) + first stage input ----
    float z[2][4], kacc[2][4];
    #pragma unroll
    for (int nt = 0; nt < 2; ++nt)
    #pragma unroll
    for (int rg = 0; rg < 4; ++rg){
        const int row = mh*16 + hi16*4 + rg;
        const int l   = qb*M_ + row;
        const int c   = nq*32 + nt*16 + r15;
        float v = x[((size_t)b*L_ + l)*E_ + c];
        z[nt][rg] = v; kacc[nt][rg] = 0.f;
        unsigned short hh = f2bf(v);
        st16(sA_hi, row, c, hh);
        st16(sA_lo, row, c, f2bf(v - bf2f(hh)));
    }

    if (tid < M_) hisq[tid] = his[qb*M_ + tid];
    if (tid < P_) dstep[tid] = (tid == 0) ? 0.f : (pre[tid] - pre[tid-1]);
    if (tid >= 64 && tid < 128){
        int p = tid - 64; float s = 0.f;
        for (int ll = 0; ll < L_; ++ll){
            float dd = fabsf(his[ll] - pre[p]);
            s += __expf(1.0f / (dd + 1e-8f));
        }
        den_s[p] = s;
    }
    const float pre0 = pre[0];
    __syncthreads();
    for (int idx = tid; idx < M_*P_; idx += NT_){
        int r = idx >> 6, p = idx & 63;
        float dd = fabsf(hisq[r] - pre[p]);
        wLP[r][p] = __expf(1.0f / (dd + 1e-8f)) / den_s[p];
    }
    // wLP first read at end of step 0: stage barriers cover the ordering.

    // ==== main scan: 64 RK4 steps ====
    for (int p = 0; p < P_; ++p){
        const float dts = dstep[p];
        for (int s = 0; s < 4; ++s){
            const float c_s = (s == 2) ? 1.0f : 0.5f;           // stage coeff for NEXT input
            const float w_s = (s == 0 || s == 3) ? 1.0f : 2.0f; // RK4 weight
            __syncthreads();                                    // S_A ready
            // --- matmul1: H = S_A @ W1 (3-term bf16 split) ---
            f32x4 accH[2] = { f32x4{0,0,0,0}, f32x4{0,0,0,0} };
            #pragma unroll
            for (int kt = 0; kt < 4; ++kt){
                const int arow = mh*16 + r15;
                const int kb   = kt*32 + hi16*8;
                bf16x8 ah = ldfrag(sA_hi, arow, kb);
                bf16x8 al = ldfrag(sA_lo, arow, kb);
                accH[0] = mfma16(ah, w1h[kt][0], accH[0]);
                accH[0] = mfma16(al, w1h[kt][0], accH[0]);
                accH[0] = mfma16(ah, w1l[kt][0], accH[0]);
                accH[1] = mfma16(ah, w1h[kt][1], accH[1]);
                accH[1] = mfma16(al, w1h[kt][1], accH[1]);
                accH[1] = mfma16(ah, w1l[kt][1], accH[1]);
            }
            // --- tanh -> S_B (safe: all waves passed prev barrier => done reading S_B) ---
            #pragma unroll
            for (int nt = 0; nt < 2; ++nt)
            #pragma unroll
            for (int rg = 0; rg < 4; ++rg){
                const int row = mh*16 + hi16*4 + rg;
                const int c   = nq*32 + nt*16 + r15;
                float t = tanh_fast(accH[nt][rg] + b1v[nt]);
                unsigned short hh = f2bf(t);
                st16(sB_hi, row, c, hh);
                st16(sB_lo, row, c, f2bf(t - bf2f(hh)));
            }
            __syncthreads();                                    // S_B ready
            // --- matmul2: K = tanh(...) @ W2 ---
            f32x4 accK[2] = { f32x4{0,0,0,0}, f32x4{0,0,0,0} };
            #pragma unroll
            for (int kt = 0; kt < 4; ++kt){
                const int arow = mh*16 + r15;
                const int kb   = kt*32 + hi16*8;
                bf16x8 ah = ldfrag(sB_hi, arow, kb);
                bf16x8 al = ldfrag(sB_lo, arow, kb);
                accK[0] = mfma16(ah, w2h[kt][0], accK[0]);
                accK[0] = mfma16(al, w2h[kt][0], accK[0]);
                accK[0] = mfma16(ah, w2l[kt][0], accK[0]);
                accK[1] = mfma16(ah, w2h[kt][1], accK[1]);
                accK[1] = mfma16(al, w2h[kt][1], accK[1]);
                accK[1] = mfma16(ah, w2l[kt][1], accK[1]);
            }
            // --- k_i, RK4 accumulate, next stage input (safe after S_B barrier) ---
            #pragma unroll
            for (int nt = 0; nt < 2; ++nt)
            #pragma unroll
            for (int rg = 0; rg < 4; ++rg){
                const int row = mh*16 + hi16*4 + rg;
                float kv = accK[nt][rg] + b2v[nt];
                kacc[nt][rg] += w_s * kv;
                if (s < 3){
                    float dtv = (p == 0) ? (pre0 - hisq[row]) : dts;
                    float sv  = z[nt][rg] + c_s * dtv * kv;
                    const int c = nq*32 + nt*16 + r15;
                    unsigned short hh = f2bf(sv);
                    st16(sA_hi, row, c, hh);
                    st16(sA_lo, row, c, f2bf(sv - bf2f(hh)));
                }
            }
        }
        // ---- zn = z + dt/6 * (k1+2k2+2k3+k4); write next k1 input; weighted reduce ----
        float po[2] = {0.f, 0.f};
        #pragma unroll
        for (int nt = 0; nt < 2; ++nt)
        #pragma unroll
        for (int rg = 0; rg < 4; ++rg){
            const int row = mh*16 + hi16*4 + rg;
            const int c   = nq*32 + nt*16 + r15;
            float dtv = (p == 0) ? (pre0 - hisq[row]) : dts;
            float zn  = z[nt][rg] + (dtv * (1.0f/6.0f)) * kacc[nt][rg];
            z[nt][rg] = zn; kacc[nt][rg] = 0.f;
            unsigned short hh = f2bf(zn);
            st16(sA_hi, row, c, hh);
            st16(sA_lo, row, c, f2bf(zn - bf2f(hh)));
            po[nt] += wLP[row][p] * zn;
        }
        #pragma unroll
        for (int nt = 0; nt < 2; ++nt){
            po[nt] += __shfl_xor(po[nt], 16);
            po[nt] += __shfl_xor(po[nt], 32);   // sum over the 16 rows of this half
        }
        if (ATOMIC){
            if (hi16 == 0){
                #pragma unroll
                for (int nt = 0; nt < 2; ++nt){
                    const int c = nq*32 + nt*16 + r15;
                    atomicAdd(&dst[((size_t)b*P_ + p)*E_ + c], po[nt]);
                }
            }
        } else {
            if (hi16 == 0){
                #pragma unroll
                for (int nt = 0; nt < 2; ++nt){
                    const int c = nq*32 + nt*16 + r15;
                    pred[mh][c] = po[nt];
                }
            }
            __syncthreads();
            if (tid < E_){
                dst[(((size_t)qb*B_ + b)*P_ + p)*E_ + tid] = pred[0][tid] + pred[1][tid];
            }
            // next write to pred is after >=8 stage barriers -> no extra barrier needed
        }
    }
}

__global__ void reduce_q(const float* __restrict__ part, float* __restrict__ out){
    const int n = B_*P_*E_;
    int i = blockIdx.x * blockDim.x + threadIdx.x;
    if (i < n)
        out[i] = (part[i] + part[i + n]) + (part[i + 2*n] + part[i + 3*n]);
}

extern "C" void kernel_launch(void* const* d_in, const int* in_sizes, int n_in,
                              void* d_out, int out_size, void* d_ws, size_t ws_size,
                              hipStream_t stream) {
    const float* x   = (const float*)d_in[0];
    const float* his = (const float*)d_in[1];
    const float* pre = (const float*)d_in[2];
    const float* W1  = (const float*)d_in[3];
    const float* b1  = (const float*)d_in[4];
    const float* W2  = (const float*)d_in[5];
    const float* b2  = (const float*)d_in[6];
    float* out = (float*)d_out;

    const size_t need = (size_t)4 * B_ * P_ * E_ * sizeof(float);  // 8 MB partials
    if (ws_size >= need){
        float* part = (float*)d_ws;
        wode_main<false><<<B_*4, NT_, 0, stream>>>(x, his, pre, W1, b1, W2, b2, part);
        const int n = B_*P_*E_;
        reduce_q<<<(n + 255)/256, 256, 0, stream>>>(part, out);
    } else {
        hipMemsetAsync(d_out, 0, (size_t)B_*P_*E_*sizeof(float), stream);
        wode_main<true><<<B_*4, NT_, 0, stream>>>(x, his, pre, W1, b1, W2, b2, out);
    }
}

// Round 2
// 417.439 us; speedup vs baseline: 1.1445x; 1.1445x over previous
//
#include <hip/hip_runtime.h>
#include <hip/hip_bf16.h>

#define B_ 64
#define L_ 128
#define P_ 64
#define E_ 128
#define H_ 128
#define M_ 16     // rows per block
#define NT_ 256   // 4 waves, one col-quarter each

typedef __attribute__((ext_vector_type(8))) short bf16x8;
typedef __attribute__((ext_vector_type(4))) float f32x4;

__device__ __forceinline__ unsigned short f2bf_rne(float f){
    unsigned u = __builtin_bit_cast(unsigned, f);
    u += 0x7fffu + ((u >> 16) & 1u);
    return (unsigned short)(u >> 16);
}
__device__ __forceinline__ float bf2f(unsigned short h){
    return __builtin_bit_cast(float, ((unsigned)h) << 16);
}
__device__ __forceinline__ float tanh_fast(float x){
    float ax = fminf(fabsf(x), 20.0f);
    float e  = __expf(2.0f * ax);
    float r  = 1.0f - 2.0f * __builtin_amdgcn_rcpf(e + 1.0f);
    return copysignf(r, x);
}
// Swizzle: C-write rows {rg,rg+4,rg+8,rg+12} -> 4 distinct 32B bank regions
// (bits 5-6 of slot<<4 distinct); frag-read rows 0..15 -> each slot 2x (free).
__device__ __forceinline__ int slotOf(int row){
    int rg = row & 3, h = row >> 2;
    return ((h ^ rg) << 1) | (rg >> 1);
}
__device__ __forceinline__ void st16(unsigned short* arr, int row, int col, unsigned v16){
    int byte = ((row << 8) + (col << 1)) ^ (slotOf(row) << 4);
    *(unsigned short*)((char*)arr + byte) = (unsigned short)v16;
}
__device__ __forceinline__ bf16x8 ldfrag(const unsigned short* arr, int row, int kb){
    int byte = ((row << 8) + (kb << 1)) ^ (slotOf(row) << 4);   // 16B aligned
    return *(const bf16x8*)((const char*)arr + byte);
}
// truncation split: hi = top 16 bits (exact and), lo = bf16_trunc(f - hi).
// a = hi + lo + eps, |eps| <= 2^-16 |a|  (cheap: and, sub, shr)
__device__ __forceinline__ void split_store(unsigned short* hi_a, unsigned short* lo_a,
                                            int row, int col, float f){
    unsigned u  = __builtin_bit_cast(unsigned, f);
    unsigned hb = u & 0xffff0000u;
    float    al = f - __builtin_bit_cast(float, hb);   // exact
    unsigned lb = __builtin_bit_cast(unsigned, al) >> 16;
    st16(hi_a, row, col, hb >> 16);
    st16(lo_a, row, col, lb);
}
__device__ __forceinline__ f32x4 mfma16(bf16x8 a, bf16x8 b, f32x4 c){
    return __builtin_amdgcn_mfma_f32_16x16x32_bf16(a, b, c, 0, 0, 0);
}

template<bool ATOMIC>
__global__ __launch_bounds__(NT_, 2) void wode_main(
    const float* __restrict__ x,   const float* __restrict__ his,
    const float* __restrict__ pre, const float* __restrict__ W1,
    const float* __restrict__ b1,  const float* __restrict__ W2,
    const float* __restrict__ b2,  float* __restrict__ dst)
{
    __shared__ __align__(16) unsigned short sA_hi[M_*E_], sA_lo[M_*E_];
    __shared__ __align__(16) unsigned short sB_hi[M_*E_], sB_lo[M_*E_];
    __shared__ float wLP[M_][P_];
    __shared__ float hisq[M_];
    __shared__ float dstep[P_];
    __shared__ float den_s[P_];

    const int tid  = threadIdx.x;
    const int lane = tid & 63;
    const int nq   = tid >> 6;        // wave = col-quarter: cols [32*nq, 32*nq+32)
    const int r15  = lane & 15;
    const int hi16 = lane >> 4;
    const int b    = blockIdx.x >> 3;
    const int qb   = blockIdx.x & 7;  // l-group: l = 16*qb + row

    // ---- weights -> hi/lo bf16 B-fragments (RNE split, one-time) ----
    bf16x8 w1h[4][2], w1l[4][2], w2h[4][2], w2l[4][2];   // [kt][nt]
    #pragma unroll
    for (int kt = 0; kt < 4; ++kt)
    #pragma unroll
    for (int nt = 0; nt < 2; ++nt){
        const int c  = nq*32 + nt*16 + r15;
        const int kb = kt*32 + hi16*8;
        bf16x8 h1, l1, h2, l2;
        #pragma unroll
        for (int j = 0; j < 8; ++j){
            float v1 = W1[(kb + j)*H_ + c];
            unsigned short hh1 = f2bf_rne(v1);
            h1[j] = (short)hh1; l1[j] = (short)f2bf_rne(v1 - bf2f(hh1));
            float v2 = W2[(kb + j)*E_ + c];
            unsigned short hh2 = f2bf_rne(v2);
            h2[j] = (short)hh2; l2[j] = (short)f2bf_rne(v2 - bf2f(hh2));
        }
        w1h[kt][nt] = h1; w1l[kt][nt] = l1;
        w2h[kt][nt] = h2; w2l[kt][nt] = l2;
    }
    float b1v[2], b2v[2];
    #pragma unroll
    for (int nt = 0; nt < 2; ++nt){
        const int c = nq*32 + nt*16 + r15;
        b1v[nt] = b1[c]; b2v[nt] = b2[c];
    }

    // ---- z init (C-fragment layout) + first stage input ----
    float z[2][4], kacc[2][4];
    #pragma unroll
    for (int nt = 0; nt < 2; ++nt)
    #pragma unroll
    for (int rg = 0; rg < 4; ++rg){
        const int row = hi16*4 + rg;
        const int l   = qb*M_ + row;
        const int c   = nq*32 + nt*16 + r15;
        float v = x[((size_t)b*L_ + l)*E_ + c];
        z[nt][rg] = v; kacc[nt][rg] = 0.f;
        split_store(sA_hi, sA_lo, row, c, v);
    }

    if (tid < M_) hisq[tid] = his[qb*M_ + tid];
    if (tid >= 64 && tid < 128){
        int p = tid - 64;
        dstep[p] = (p == 0) ? 0.f : (pre[p] - pre[p-1]);
    }
    if (tid >= 128 && tid < 192){
        int p = tid - 128; float s = 0.f;
        for (int ll = 0; ll < L_; ++ll){
            float dd = fabsf(his[ll] - pre[p]);
            s += __expf(1.0f / (dd + 1e-8f));
        }
        den_s[p] = s;
    }
    const float pre0 = pre[0];
    __syncthreads();
    for (int idx = tid; idx < M_*P_; idx += NT_){
        int r = idx >> 6, p = idx & 63;
        float dd = fabsf(hisq[r] - pre[p]);
        wLP[r][p] = __expf(1.0f / (dd + 1e-8f)) / den_s[p];
    }
    // wLP first read after step-0 stage barriers -> ordered.

    // ==== main scan: 64 RK4 steps ====
    for (int p = 0; p < P_; ++p){
        const float dts = dstep[p];
        for (int s = 0; s < 4; ++s){
            const float c_s = (s == 2) ? 1.0f : 0.5f;
            const float w_s = (s == 0 || s == 3) ? 1.0f : 2.0f;
            __syncthreads();                                    // S_A ready
            // --- matmul1: H = S_A @ W1 (4 independent acc chains) ---
            f32x4 acc[2][2] = {{{0,0,0,0},{0,0,0,0}},{{0,0,0,0},{0,0,0,0}}};
            #pragma unroll
            for (int kt = 0; kt < 4; ++kt){
                const int kb = kt*32 + hi16*8;
                bf16x8 ah = ldfrag(sA_hi, r15, kb);
                bf16x8 al = ldfrag(sA_lo, r15, kb);
                const int hf = kt >> 1;
                acc[0][hf] = mfma16(ah, w1h[kt][0], acc[0][hf]);
                acc[0][hf] = mfma16(al, w1h[kt][0], acc[0][hf]);
                acc[0][hf] = mfma16(ah, w1l[kt][0], acc[0][hf]);
                acc[1][hf] = mfma16(ah, w1h[kt][1], acc[1][hf]);
                acc[1][hf] = mfma16(al, w1h[kt][1], acc[1][hf]);
                acc[1][hf] = mfma16(ah, w1l[kt][1], acc[1][hf]);
            }
            // --- tanh -> S_B ---
            #pragma unroll
            for (int nt = 0; nt < 2; ++nt)
            #pragma unroll
            for (int rg = 0; rg < 4; ++rg){
                const int row = hi16*4 + rg;
                const int c   = nq*32 + nt*16 + r15;
                float t = tanh_fast(acc[nt][0][rg] + acc[nt][1][rg] + b1v[nt]);
                split_store(sB_hi, sB_lo, row, c, t);
            }
            __syncthreads();                                    // S_B ready
            // --- matmul2: K = tanh(...) @ W2 ---
            f32x4 acd[2][2] = {{{0,0,0,0},{0,0,0,0}},{{0,0,0,0},{0,0,0,0}}};
            #pragma unroll
            for (int kt = 0; kt < 4; ++kt){
                const int kb = kt*32 + hi16*8;
                bf16x8 ah = ldfrag(sB_hi, r15, kb);
                bf16x8 al = ldfrag(sB_lo, r15, kb);
                const int hf = kt >> 1;
                acd[0][hf] = mfma16(ah, w2h[kt][0], acd[0][hf]);
                acd[0][hf] = mfma16(al, w2h[kt][0], acd[0][hf]);
                acd[0][hf] = mfma16(ah, w2l[kt][0], acd[0][hf]);
                acd[1][hf] = mfma16(ah, w2h[kt][1], acd[1][hf]);
                acd[1][hf] = mfma16(al, w2h[kt][1], acd[1][hf]);
                acd[1][hf] = mfma16(ah, w2l[kt][1], acd[1][hf]);
            }
            // --- k_i, RK4 accumulate, next stage input ---
            #pragma unroll
            for (int nt = 0; nt < 2; ++nt)
            #pragma unroll
            for (int rg = 0; rg < 4; ++rg){
                const int row = hi16*4 + rg;
                float kv = acd[nt][0][rg] + acd[nt][1][rg] + b2v[nt];
                kacc[nt][rg] += w_s * kv;
                if (s < 3){
                    float dtv = (p == 0) ? (pre0 - hisq[row]) : dts;
                    float sv  = z[nt][rg] + c_s * dtv * kv;
                    const int c = nq*32 + nt*16 + r15;
                    split_store(sA_hi, sA_lo, row, c, sv);
                }
            }
        }
        // ---- zn update, next k1 input, weighted reduce, output ----
        float po[2] = {0.f, 0.f};
        #pragma unroll
        for (int nt = 0; nt < 2; ++nt)
        #pragma unroll
        for (int rg = 0; rg < 4; ++rg){
            const int row = hi16*4 + rg;
            const int c   = nq*32 + nt*16 + r15;
            float dtv = (p == 0) ? (pre0 - hisq[row]) : dts;
            float zn  = z[nt][rg] + (dtv * (1.0f/6.0f)) * kacc[nt][rg];
            z[nt][rg] = zn; kacc[nt][rg] = 0.f;
            split_store(sA_hi, sA_lo, row, c, zn);
            po[nt] += wLP[row][p] * zn;
        }
        #pragma unroll
        for (int nt = 0; nt < 2; ++nt){
            po[nt] += __shfl_xor(po[nt], 16);
            po[nt] += __shfl_xor(po[nt], 32);   // sum over all 16 rows
        }
        if (hi16 == 0){
            #pragma unroll
            for (int nt = 0; nt < 2; ++nt){
                const int c = nq*32 + nt*16 + r15;
                if (ATOMIC)
                    atomicAdd(&dst[((size_t)b*P_ + p)*E_ + c], po[nt]);
                else
                    dst[(((size_t)qb*B_ + b)*P_ + p)*E_ + c] = po[nt];
            }
        }
    }
}

__global__ void reduce_q(const float* __restrict__ part, float* __restrict__ out){
    const int n = B_*P_*E_;
    int i = blockIdx.x * blockDim.x + threadIdx.x;
    if (i < n){
        float s0 = part[i]       + part[i + n];
        float s1 = part[i + 2*n] + part[i + 3*n];
        float s2 = part[i + 4*n] + part[i + 5*n];
        float s3 = part[i + 6*n] + part[i + 7*n];
        out[i] = (s0 + s1) + (s2 + s3);
    }
}

extern "C" void kernel_launch(void* const* d_in, const int* in_sizes, int n_in,
                              void* d_out, int out_size, void* d_ws, size_t ws_size,
                              hipStream_t stream) {
    const float* x   = (const float*)d_in[0];
    const float* his = (const float*)d_in[1];
    const float* pre = (const float*)d_in[2];
    const float* W1  = (const float*)d_in[3];
    const float* b1  = (const float*)d_in[4];
    const float* W2  = (const float*)d_in[5];
    const float* b2  = (const float*)d_in[6];
    float* out = (float*)d_out;

    const size_t need = (size_t)8 * B_ * P_ * E_ * sizeof(float);  // 16 MB partials
    if (ws_size >= need){
        float* part = (float*)d_ws;
        wode_main<false><<<B_*8, NT_, 0, stream>>>(x, his, pre, W1, b1, W2, b2, part);
        const int n = B_*P_*E_;
        reduce_q<<<(n + 255)/256, 256, 0, stream>>>(part, out);
    } else {
        hipMemsetAsync(d_out, 0, (size_t)B_*P_*E_*sizeof(float), stream);
        wode_main<true><<<B_*8, NT_, 0, stream>>>(x, his, pre, W1, b1, W2, b2, out);
    }
}

// Round 3
// 314.780 us; speedup vs baseline: 1.5178x; 1.3261x over previous
//
#include <hip/hip_runtime.h>
#include <hip/hip_bf16.h>

#define B_ 64
#define L_ 128
#define P_ 64
#define E_ 128
#define H_ 128
#define M_ 16     // rows per block
#define NT_ 256   // 4 waves, one col-quarter each

typedef _Float16 f16x8 __attribute__((ext_vector_type(8)));
typedef float    f32x4 __attribute__((ext_vector_type(4)));

__device__ __forceinline__ float tanh_fast(float x){
    // tanh(x) = sign(x) * (1 - 2/(exp(2|x|)+1)); exp2 overflow -> rcp(inf)=0 -> 1. OK.
    float e = __builtin_exp2f(fabsf(x) * 2.885390082f);   // exp(2|x|)
    float r = 1.0f - 2.0f * __builtin_amdgcn_rcpf(e + 1.0f);
    return copysignf(r, x);
}
// Swizzle: C-write rows {rg,rg+4,rg+8,rg+12} -> 4 distinct 32B bank regions;
// frag-read rows 0..15 -> each 16B slot hit exactly 2x (2-way = free).
__device__ __forceinline__ int slotOf(int row){
    int rg = row & 3, h = row >> 2;
    return ((h ^ rg) << 1) | (rg >> 1);
}
__device__ __forceinline__ void stf16(_Float16* arr, int row, int col, float f){
    int byte = ((row << 8) + (col << 1)) ^ (slotOf(row) << 4);
    *(_Float16*)((char*)arr + byte) = (_Float16)f;
}
__device__ __forceinline__ f16x8 ldfrag(const _Float16* arr, int row, int kb){
    int byte = ((row << 8) + (kb << 1)) ^ (slotOf(row) << 4);   // 16B aligned
    return *(const f16x8*)((const char*)arr + byte);
}
__device__ __forceinline__ f32x4 mfma16(f16x8 a, f16x8 b, f32x4 c){
    return __builtin_amdgcn_mfma_f32_16x16x32_f16(a, b, c, 0, 0, 0);
}

template<bool ATOMIC>
__global__ __launch_bounds__(NT_, 2) void wode_main(
    const float* __restrict__ x,   const float* __restrict__ his,
    const float* __restrict__ pre, const float* __restrict__ W1,
    const float* __restrict__ b1,  const float* __restrict__ W2,
    const float* __restrict__ b2,  float* __restrict__ dst)
{
    __shared__ __align__(16) _Float16 sA[M_*E_];   // stage input, f16
    __shared__ __align__(16) _Float16 sB[M_*E_];   // tanh intermediate, f16
    __shared__ float wLP[M_][P_];
    __shared__ float hisq[M_];
    __shared__ float dstep[P_];
    __shared__ float den_s[P_];

    const int tid  = threadIdx.x;
    const int lane = tid & 63;
    const int nq   = tid >> 6;        // wave = col-quarter: cols [32*nq, 32*nq+32)
    const int r15  = lane & 15;
    const int hi16 = lane >> 4;       // 0..3
    const int b    = blockIdx.x >> 3;
    const int qb   = blockIdx.x & 7;  // l-group: l = 16*qb + row

    // ---- weights -> 2-term f16 B-fragments in registers (exact to ~2^-21) ----
    f16x8 w1h[4][2], w1l[4][2], w2h[4][2], w2l[4][2];   // [kt][nt]
    #pragma unroll
    for (int kt = 0; kt < 4; ++kt)
    #pragma unroll
    for (int nt = 0; nt < 2; ++nt){
        const int c  = nq*32 + nt*16 + r15;
        const int kb = kt*32 + hi16*8;
        f16x8 h1, l1, h2, l2;
        #pragma unroll
        for (int j = 0; j < 8; ++j){
            float v1 = W1[(kb + j)*H_ + c];
            _Float16 hh1 = (_Float16)v1;
            h1[j] = hh1; l1[j] = (_Float16)(v1 - (float)hh1);
            float v2 = W2[(kb + j)*E_ + c];
            _Float16 hh2 = (_Float16)v2;
            h2[j] = hh2; l2[j] = (_Float16)(v2 - (float)hh2);
        }
        w1h[kt][nt] = h1; w1l[kt][nt] = l1;
        w2h[kt][nt] = h2; w2l[kt][nt] = l2;
    }
    float b1v[2], b2v[2];
    #pragma unroll
    for (int nt = 0; nt < 2; ++nt){
        const int c = nq*32 + nt*16 + r15;
        b1v[nt] = b1[c]; b2v[nt] = b2[c];
    }

    // ---- z init (C-fragment layout) + first stage input ----
    float z[2][4], kacc[2][4];
    #pragma unroll
    for (int nt = 0; nt < 2; ++nt)
    #pragma unroll
    for (int rg = 0; rg < 4; ++rg){
        const int row = hi16*4 + rg;
        const int l   = qb*M_ + row;
        const int c   = nq*32 + nt*16 + r15;
        float v = x[((size_t)b*L_ + l)*E_ + c];
        z[nt][rg] = v; kacc[nt][rg] = 0.f;
        stf16(sA, row, c, v);
    }

    if (tid < M_) hisq[tid] = his[qb*M_ + tid];
    if (tid >= 64 && tid < 128){
        int p = tid - 64;
        dstep[p] = (p == 0) ? 0.f : (pre[p] - pre[p-1]);
    }
    if (tid >= 128 && tid < 192){
        int p = tid - 128; float s = 0.f;
        for (int ll = 0; ll < L_; ++ll){
            float dd = fabsf(his[ll] - pre[p]);
            s += __expf(1.0f / (dd + 1e-8f));
        }
        den_s[p] = s;
    }
    const float pre0 = pre[0];
    __syncthreads();
    for (int idx = tid; idx < M_*P_; idx += NT_){
        int r = idx >> 6, p = idx & 63;
        float dd = fabsf(hisq[r] - pre[p]);
        wLP[r][p] = __expf(1.0f / (dd + 1e-8f)) / den_s[p];
    }
    // wLP first read after step-0 stage barriers -> ordered.

    // ==== main scan: 64 RK4 steps ====
    for (int p = 0; p < P_; ++p){
        const float dts = dstep[p];
        for (int s = 0; s < 4; ++s){
            const float c_s = (s == 2) ? 1.0f : 0.5f;
            const float w_s = (s == 0 || s == 3) ? 1.0f : 2.0f;
            __syncthreads();                                    // S_A ready
            // --- matmul1: H = S_A @ W1 (2-term f16; bias folded into acc init) ---
            f32x4 acc[2][2];
            #pragma unroll
            for (int nt = 0; nt < 2; ++nt){
                acc[nt][0] = f32x4{b1v[nt], b1v[nt], b1v[nt], b1v[nt]};
                acc[nt][1] = f32x4{0,0,0,0};
            }
            #pragma unroll
            for (int kt = 0; kt < 4; ++kt){
                f16x8 a = ldfrag(sA, r15, kt*32 + hi16*8);
                const int hf = kt >> 1;
                acc[0][hf] = mfma16(a, w1h[kt][0], acc[0][hf]);
                acc[0][hf] = mfma16(a, w1l[kt][0], acc[0][hf]);
                acc[1][hf] = mfma16(a, w1h[kt][1], acc[1][hf]);
                acc[1][hf] = mfma16(a, w1l[kt][1], acc[1][hf]);
            }
            // --- tanh -> S_B ---
            #pragma unroll
            for (int nt = 0; nt < 2; ++nt)
            #pragma unroll
            for (int rg = 0; rg < 4; ++rg){
                const int row = hi16*4 + rg;
                const int c   = nq*32 + nt*16 + r15;
                stf16(sB, row, c, tanh_fast(acc[nt][0][rg] + acc[nt][1][rg]));
            }
            __syncthreads();                                    // S_B ready
            // --- matmul2: K = tanh(...) @ W2 ---
            f32x4 acd[2][2];
            #pragma unroll
            for (int nt = 0; nt < 2; ++nt){
                acd[nt][0] = f32x4{b2v[nt], b2v[nt], b2v[nt], b2v[nt]};
                acd[nt][1] = f32x4{0,0,0,0};
            }
            #pragma unroll
            for (int kt = 0; kt < 4; ++kt){
                f16x8 a = ldfrag(sB, r15, kt*32 + hi16*8);
                const int hf = kt >> 1;
                acd[0][hf] = mfma16(a, w2h[kt][0], acd[0][hf]);
                acd[0][hf] = mfma16(a, w2l[kt][0], acd[0][hf]);
                acd[1][hf] = mfma16(a, w2h[kt][1], acd[1][hf]);
                acd[1][hf] = mfma16(a, w2l[kt][1], acd[1][hf]);
            }
            // --- k_i, RK4 accumulate, next stage input ---
            #pragma unroll
            for (int nt = 0; nt < 2; ++nt)
            #pragma unroll
            for (int rg = 0; rg < 4; ++rg){
                const int row = hi16*4 + rg;
                float kv = acd[nt][0][rg] + acd[nt][1][rg];
                kacc[nt][rg] += w_s * kv;
                if (s < 3){
                    float dtv = (p == 0) ? (pre0 - hisq[row]) : dts;
                    float sv  = z[nt][rg] + c_s * dtv * kv;
                    const int c = nq*32 + nt*16 + r15;
                    stf16(sA, row, c, sv);
                }
            }
        }
        // ---- zn update, next k1 input, weighted reduce, output ----
        float po[2] = {0.f, 0.f};
        #pragma unroll
        for (int nt = 0; nt < 2; ++nt)
        #pragma unroll
        for (int rg = 0; rg < 4; ++rg){
            const int row = hi16*4 + rg;
            const int c   = nq*32 + nt*16 + r15;
            float dtv = (p == 0) ? (pre0 - hisq[row]) : dts;
            float zn  = z[nt][rg] + (dtv * (1.0f/6.0f)) * kacc[nt][rg];
            z[nt][rg] = zn; kacc[nt][rg] = 0.f;
            stf16(sA, row, c, zn);
            po[nt] += wLP[row][p] * zn;
        }
        #pragma unroll
        for (int nt = 0; nt < 2; ++nt){
            po[nt] += __shfl_xor(po[nt], 16);
            po[nt] += __shfl_xor(po[nt], 32);   // sum over all 16 rows
        }
        if (hi16 == 0){
            #pragma unroll
            for (int nt = 0; nt < 2; ++nt){
                const int c = nq*32 + nt*16 + r15;
                if (ATOMIC)
                    atomicAdd(&dst[((size_t)b*P_ + p)*E_ + c], po[nt]);
                else
                    dst[(((size_t)qb*B_ + b)*P_ + p)*E_ + c] = po[nt];
            }
        }
    }
}

__global__ void reduce_q(const float* __restrict__ part, float* __restrict__ out){
    const int n = B_*P_*E_;
    int i = blockIdx.x * blockDim.x + threadIdx.x;
    if (i < n){
        float s0 = part[i]       + part[i + n];
        float s1 = part[i + 2*n] + part[i + 3*n];
        float s2 = part[i + 4*n] + part[i + 5*n];
        float s3 = part[i + 6*n] + part[i + 7*n];
        out[i] = (s0 + s1) + (s2 + s3);
    }
}

extern "C" void kernel_launch(void* const* d_in, const int* in_sizes, int n_in,
                              void* d_out, int out_size, void* d_ws, size_t ws_size,
                              hipStream_t stream) {
    const float* x   = (const float*)d_in[0];
    const float* his = (const float*)d_in[1];
    const float* pre = (const float*)d_in[2];
    const float* W1  = (const float*)d_in[3];
    const float* b1  = (const float*)d_in[4];
    const float* W2  = (const float*)d_in[5];
    const float* b2  = (const float*)d_in[6];
    float* out = (float*)d_out;

    const size_t need = (size_t)8 * B_ * P_ * E_ * sizeof(float);  // 16 MB partials
    if (ws_size >= need){
        float* part = (float*)d_ws;
        wode_main<false><<<B_*8, NT_, 0, stream>>>(x, his, pre, W1, b1, W2, b2, part);
        const int n = B_*P_*E_;
        reduce_q<<<(n + 255)/256, 256, 0, stream>>>(part, out);
    } else {
        hipMemsetAsync(d_out, 0, (size_t)B_*P_*E_*sizeof(float), stream);
        wode_main<true><<<B_*8, NT_, 0, stream>>>(x, his, pre, W1, b1, W2, b2, out);
    }
}

// Round 4
// 275.008 us; speedup vs baseline: 1.7373x; 1.1446x over previous
//
#include <hip/hip_runtime.h>
#include <hip/hip_bf16.h>

#define B_ 64
#define L_ 128
#define P_ 64
#define E_ 128
#define H_ 128
#define M_ 16     // rows per block
#define NT_ 256   // 4 waves, one col-quarter each

typedef _Float16 f16x8 __attribute__((ext_vector_type(8)));
typedef float    f32x4 __attribute__((ext_vector_type(4)));

__device__ __forceinline__ float tanh_fast(float x){
    // clamp to +-8 (tanh saturates), then (e-1)/(e+1), e = exp(2x) via exp2
    float xc = fminf(fmaxf(x, -8.0f), 8.0f);
    float e  = __builtin_exp2f(xc * 2.885390082f);
    return (e - 1.0f) * __builtin_amdgcn_rcpf(e + 1.0f);
}
// Swizzle: C-write rows {rg,rg+4,rg+8,rg+12} -> 4 distinct 32B bank regions;
// frag-read rows 0..15 -> each 16B slot hit exactly 2x (2-way = free).
__device__ __forceinline__ int slotOf(int row){
    int rg = row & 3, h = row >> 2;
    return ((h ^ rg) << 1) | (rg >> 1);
}
__device__ __forceinline__ int lds_byte(int row, int col){
    return ((row << 8) + (col << 1)) ^ (slotOf(row) << 4);
}
__device__ __forceinline__ f32x4 mfma16(f16x8 a, f16x8 b, f32x4 c){
    return __builtin_amdgcn_mfma_f32_16x16x32_f16(a, b, c, 0, 0, 0);
}

template<bool ATOMIC>
__global__ __launch_bounds__(NT_, 2) void wode_main(
    const float* __restrict__ x,   const float* __restrict__ his,
    const float* __restrict__ pre, const float* __restrict__ W1,
    const float* __restrict__ b1,  const float* __restrict__ W2,
    const float* __restrict__ b2,  float* __restrict__ dst)
{
    __shared__ __align__(16) _Float16 sA[M_*E_];   // stage input, f16
    __shared__ __align__(16) _Float16 sB[M_*E_];   // tanh intermediate, f16
    __shared__ float wLP[M_][P_];
    __shared__ float hisq[M_];
    __shared__ float dstep[P_];
    __shared__ float den_s[P_];

    const int tid  = threadIdx.x;
    const int lane = tid & 63;
    const int nq   = tid >> 6;        // wave = col-quarter: cols [32*nq, 32*nq+32)
    const int r15  = lane & 15;
    const int hi16 = lane >> 4;       // 0..3
    const int b    = blockIdx.x >> 3;
    const int qb   = blockIdx.x & 7;  // l-group: l = 16*qb + row

    // ---- weights -> single f16 B-fragments in registers (RNE) ----
    f16x8 w1f[4][2], w2f[4][2];   // [kt][nt]
    #pragma unroll
    for (int kt = 0; kt < 4; ++kt)
    #pragma unroll
    for (int nt = 0; nt < 2; ++nt){
        const int c  = nq*32 + nt*16 + r15;
        const int kb = kt*32 + hi16*8;
        f16x8 h1, h2;
        #pragma unroll
        for (int j = 0; j < 8; ++j){
            h1[j] = (_Float16)W1[(kb + j)*H_ + c];
            h2[j] = (_Float16)W2[(kb + j)*E_ + c];
        }
        w1f[kt][nt] = h1; w2f[kt][nt] = h2;
    }
    float b1v[2], b2v[2];
    #pragma unroll
    for (int nt = 0; nt < 2; ++nt){
        const int c = nq*32 + nt*16 + r15;
        b1v[nt] = b1[c]; b2v[nt] = b2[c];
    }

    // ---- precomputed LDS byte addresses (loop-invariant) ----
    int rdoff[4];                 // frag-read offsets (same for sA/sB)
    #pragma unroll
    for (int kt = 0; kt < 4; ++kt)
        rdoff[kt] = lds_byte(r15, kt*32 + hi16*8);
    _Float16* stA[2][4];          // store ptrs into sA
    _Float16* stB[2][4];          // store ptrs into sB
    #pragma unroll
    for (int nt = 0; nt < 2; ++nt)
    #pragma unroll
    for (int rg = 0; rg < 4; ++rg){
        const int row = hi16*4 + rg;
        const int c   = nq*32 + nt*16 + r15;
        const int off = lds_byte(row, c);
        stA[nt][rg] = (_Float16*)((char*)sA + off);
        stB[nt][rg] = (_Float16*)((char*)sB + off);
    }

    // ---- z init (C-fragment layout) + first stage input ----
    float z[2][4], kacc[2][4];
    #pragma unroll
    for (int nt = 0; nt < 2; ++nt)
    #pragma unroll
    for (int rg = 0; rg < 4; ++rg){
        const int row = hi16*4 + rg;
        const int l   = qb*M_ + row;
        const int c   = nq*32 + nt*16 + r15;
        float v = x[((size_t)b*L_ + l)*E_ + c];
        z[nt][rg] = v; kacc[nt][rg] = 0.f;
        *stA[nt][rg] = (_Float16)v;
    }
    float dtv0[4];                // p==0 per-row dt
    #pragma unroll
    for (int rg = 0; rg < 4; ++rg)
        dtv0[rg] = 0.f;           // filled after hisq ready

    if (tid < M_) hisq[tid] = his[qb*M_ + tid];
    if (tid >= 64 && tid < 128){
        int p = tid - 64;
        dstep[p] = (p == 0) ? 0.f : (pre[p] - pre[p-1]);
    }
    if (tid >= 128 && tid < 192){
        int p = tid - 128; float s = 0.f;
        for (int ll = 0; ll < L_; ++ll){
            float dd = fabsf(his[ll] - pre[p]);
            s += __expf(1.0f / (dd + 1e-8f));
        }
        den_s[p] = s;
    }
    const float pre0 = pre[0];
    __syncthreads();
    #pragma unroll
    for (int rg = 0; rg < 4; ++rg)
        dtv0[rg] = pre0 - hisq[hi16*4 + rg];
    for (int idx = tid; idx < M_*P_; idx += NT_){
        int r = idx >> 6, p = idx & 63;
        float dd = fabsf(hisq[r] - pre[p]);
        wLP[r][p] = __expf(1.0f / (dd + 1e-8f)) / den_s[p];
    }
    // wLP first read after step-0 stage barriers -> ordered.

    // ==== main scan: 64 RK4 steps ====
    for (int p = 0; p < P_; ++p){
        const float dts = dstep[p];
        float dtv[4];
        #pragma unroll
        for (int rg = 0; rg < 4; ++rg)
            dtv[rg] = (p == 0) ? dtv0[rg] : dts;   // uniform branch, once per p
        for (int s = 0; s < 4; ++s){
            const float c_s = (s == 2) ? 1.0f : 0.5f;
            const float w_s = (s == 0 || s == 3) ? 1.0f : 2.0f;
            __syncthreads();                                    // S_A ready
            // --- matmul1: H = S_A @ W1 (bias folded into acc init) ---
            f32x4 acc[2][2];
            #pragma unroll
            for (int nt = 0; nt < 2; ++nt){
                acc[nt][0] = f32x4{b1v[nt], b1v[nt], b1v[nt], b1v[nt]};
                acc[nt][1] = f32x4{0,0,0,0};
            }
            #pragma unroll
            for (int kt = 0; kt < 4; ++kt){
                f16x8 a = *(const f16x8*)((const char*)sA + rdoff[kt]);
                const int hf = kt >> 1;
                acc[0][hf] = mfma16(a, w1f[kt][0], acc[0][hf]);
                acc[1][hf] = mfma16(a, w1f[kt][1], acc[1][hf]);
            }
            // --- tanh -> S_B ---
            #pragma unroll
            for (int nt = 0; nt < 2; ++nt)
            #pragma unroll
            for (int rg = 0; rg < 4; ++rg)
                *stB[nt][rg] = (_Float16)tanh_fast(acc[nt][0][rg] + acc[nt][1][rg]);
            __syncthreads();                                    // S_B ready
            // --- matmul2: K = tanh(...) @ W2 ---
            f32x4 acd[2][2];
            #pragma unroll
            for (int nt = 0; nt < 2; ++nt){
                acd[nt][0] = f32x4{b2v[nt], b2v[nt], b2v[nt], b2v[nt]};
                acd[nt][1] = f32x4{0,0,0,0};
            }
            #pragma unroll
            for (int kt = 0; kt < 4; ++kt){
                f16x8 a = *(const f16x8*)((const char*)sB + rdoff[kt]);
                const int hf = kt >> 1;
                acd[0][hf] = mfma16(a, w2f[kt][0], acd[0][hf]);
                acd[1][hf] = mfma16(a, w2f[kt][1], acd[1][hf]);
            }
            // --- k_i, RK4 accumulate, next stage input ---
            #pragma unroll
            for (int nt = 0; nt < 2; ++nt)
            #pragma unroll
            for (int rg = 0; rg < 4; ++rg){
                float kv = acd[nt][0][rg] + acd[nt][1][rg];
                kacc[nt][rg] += w_s * kv;
                if (s < 3){
                    float sv = z[nt][rg] + c_s * dtv[rg] * kv;
                    *stA[nt][rg] = (_Float16)sv;
                }
            }
        }
        // ---- zn update, next k1 input, weighted reduce, output ----
        float po[2] = {0.f, 0.f};
        #pragma unroll
        for (int nt = 0; nt < 2; ++nt)
        #pragma unroll
        for (int rg = 0; rg < 4; ++rg){
            const int row = hi16*4 + rg;
            float zn = z[nt][rg] + (dtv[rg] * (1.0f/6.0f)) * kacc[nt][rg];
            z[nt][rg] = zn; kacc[nt][rg] = 0.f;
            *stA[nt][rg] = (_Float16)zn;
            po[nt] += wLP[row][p] * zn;
        }
        #pragma unroll
        for (int nt = 0; nt < 2; ++nt){
            po[nt] += __shfl_xor(po[nt], 16);
            po[nt] += __shfl_xor(po[nt], 32);   // sum over all 16 rows
        }
        if (hi16 == 0){
            #pragma unroll
            for (int nt = 0; nt < 2; ++nt){
                const int c = nq*32 + nt*16 + r15;
                if (ATOMIC)
                    atomicAdd(&dst[((size_t)b*P_ + p)*E_ + c], po[nt]);
                else
                    dst[(((size_t)qb*B_ + b)*P_ + p)*E_ + c] = po[nt];
            }
        }
    }
}

__global__ void reduce_q(const float* __restrict__ part, float* __restrict__ out){
    const int n = B_*P_*E_;
    int i = blockIdx.x * blockDim.x + threadIdx.x;
    if (i < n){
        float s0 = part[i]       + part[i + n];
        float s1 = part[i + 2*n] + part[i + 3*n];
        float s2 = part[i + 4*n] + part[i + 5*n];
        float s3 = part[i + 6*n] + part[i + 7*n];
        out[i] = (s0 + s1) + (s2 + s3);
    }
}

extern "C" void kernel_launch(void* const* d_in, const int* in_sizes, int n_in,
                              void* d_out, int out_size, void* d_ws, size_t ws_size,
                              hipStream_t stream) {
    const float* x   = (const float*)d_in[0];
    const float* his = (const float*)d_in[1];
    const float* pre = (const float*)d_in[2];
    const float* W1  = (const float*)d_in[3];
    const float* b1  = (const float*)d_in[4];
    const float* W2  = (const float*)d_in[5];
    const float* b2  = (const float*)d_in[6];
    float* out = (float*)d_out;

    const size_t need = (size_t)8 * B_ * P_ * E_ * sizeof(float);  // 16 MB partials
    if (ws_size >= need){
        float* part = (float*)d_ws;
        wode_main<false><<<B_*8, NT_, 0, stream>>>(x, his, pre, W1, b1, W2, b2, part);
        const int n = B_*P_*E_;
        reduce_q<<<(n + 255)/256, 256, 0, stream>>>(part, out);
    } else {
        hipMemsetAsync(d_out, 0, (size_t)B_*P_*E_*sizeof(float), stream);
        wode_main<true><<<B_*8, NT_, 0, stream>>>(x, his, pre, W1, b1, W2, b2, out);
    }
}

// Round 7
// 228.132 us; speedup vs baseline: 2.0942x; 1.2055x over previous
//
#include <hip/hip_runtime.h>
#include <hip/hip_bf16.h>

#define B_ 64
#define L_ 128
#define P_ 64
#define E_ 128
#define H_ 128
#define M_ 16     // rows per block
#define NT_ 256   // 4 waves, one col-quarter each

typedef _Float16 f16x8 __attribute__((ext_vector_type(8)));
typedef _Float16 f16x2 __attribute__((ext_vector_type(2)));
typedef float    f32x4 __attribute__((ext_vector_type(4)));

__device__ __forceinline__ f16x2 pk16(float a, float b){
    return __builtin_bit_cast(f16x2, __builtin_amdgcn_cvt_pkrtz(a, b));
}
__device__ __forceinline__ float tanh_fast(float x){
    // 1 - 2/(exp(2x)+1). x->+inf: exp2->inf, rcp->0 -> 1. x->-inf: exp2->0 -> -1.
    float e = __builtin_exp2f(x * 2.885390082f);
    return __builtin_fmaf(-2.0f, __builtin_amdgcn_rcpf(e + 1.0f), 1.0f);
}
// Swizzle: C-write rows {rg,rg+4,rg+8,rg+12} -> 4 distinct 32B bank regions;
// frag-read rows 0..15 -> each 16B slot hit exactly 2x (2-way = free).
__device__ __forceinline__ int slotOf(int row){
    int rg = row & 3, h = row >> 2;
    return ((h ^ rg) << 1) | (rg >> 1);
}
__device__ __forceinline__ int lds_byte(int row, int col){   // col in f16 units
    return ((row << 8) + (col << 1)) ^ (slotOf(row) << 4);
}
__device__ __forceinline__ f32x4 mfma16(f16x8 a, f16x8 b, f32x4 c){
    return __builtin_amdgcn_mfma_f32_16x16x32_f16(a, b, c, 0, 0, 0);
}

// k-storage permutation: within each 32-col block, true col (nt*16 + r) is
// stored at position (2r + nt). Applied identically to sA/sB tiles and to the
// corresponding weight-fragment k-order (MFMA invariant under shared k-perm).
// stored pos s -> true col offset: 16*(s&1) + (s>>1).

template<bool ATOMIC>
__global__ __launch_bounds__(NT_, 2) void wode_main(
    const float* __restrict__ x,   const float* __restrict__ his,
    const float* __restrict__ pre, const float* __restrict__ W1,
    const float* __restrict__ b1,  const float* __restrict__ W2,
    const float* __restrict__ b2,  float* __restrict__ dst)
{
    __shared__ __align__(16) _Float16 sA[M_*E_];   // stage input, f16 (perm layout)
    __shared__ __align__(16) _Float16 sB[M_*E_];   // tanh intermediate, f16 (perm layout)
    __shared__ float wLP[M_][P_];
    __shared__ float hisq[M_];
    __shared__ float dstep[P_];
    __shared__ float den_s[P_];

    const int tid  = threadIdx.x;
    const int lane = tid & 63;
    const int nq   = tid >> 6;        // wave = col-quarter: cols [32*nq, 32*nq+32)
    const int r15  = lane & 15;
    const int hi16 = lane >> 4;       // 0..3
    const int b    = blockIdx.x >> 3;
    const int qb   = blockIdx.x & 7;  // l-group: l = 16*qb + row

    // ---- weights -> single f16 B-fragments, k-order matching stored layout ----
    f16x8 w1f[4][2], w2f[4][2];   // [kt][nt]
    #pragma unroll
    for (int kt = 0; kt < 4; ++kt)
    #pragma unroll
    for (int nt = 0; nt < 2; ++nt){
        const int c = nq*32 + nt*16 + r15;
        f16x8 h1, h2;
        #pragma unroll
        for (int j = 0; j < 8; ++j){
            // stored k = kt*32 + hi16*8 + j  ->  true k:
            const int ok = kt*32 + hi16*4 + (j >> 1) + 16*(j & 1);
            h1[j] = (_Float16)W1[ok*H_ + c];
            h2[j] = (_Float16)W2[ok*E_ + c];
        }
        w1f[kt][nt] = h1; w2f[kt][nt] = h2;
    }
    float b1v[2], b2v[2];
    #pragma unroll
    for (int nt = 0; nt < 2; ++nt){
        const int c = nq*32 + nt*16 + r15;
        b1v[nt] = b1[c]; b2v[nt] = b2[c];
    }

    // ---- precomputed LDS addresses ----
    int rdoff[4];                 // frag-read byte offsets (same for sA/sB)
    #pragma unroll
    for (int kt = 0; kt < 4; ++kt)
        rdoff[kt] = lds_byte(r15, kt*32 + hi16*8);
    f16x2* stA32[4];              // paired stores: true cols (nq*32+r15, +16)
    f16x2* stB32[4];
    #pragma unroll
    for (int rg = 0; rg < 4; ++rg){
        const int row = hi16*4 + rg;
        const int off = lds_byte(row, nq*32 + 2*r15);   // 4B-aligned
        stA32[rg] = (f16x2*)((char*)sA + off);
        stB32[rg] = (f16x2*)((char*)sB + off);
    }

    // ---- z init (C-fragment layout) + first stage input ----
    float z[2][4], kacc[2][4];
    #pragma unroll
    for (int rg = 0; rg < 4; ++rg){
        const int row = hi16*4 + rg;
        const int l   = qb*M_ + row;
        const size_t base = ((size_t)b*L_ + l)*E_;
        float v0 = x[base + nq*32 + r15];
        float v1 = x[base + nq*32 + 16 + r15];
        z[0][rg] = v0; z[1][rg] = v1;
        kacc[0][rg] = 0.f; kacc[1][rg] = 0.f;
        *stA32[rg] = pk16(v0, v1);
    }

    if (tid < M_) hisq[tid] = his[qb*M_ + tid];
    if (tid >= 64 && tid < 128){
        int p = tid - 64;
        dstep[p] = (p == 0) ? 0.f : (pre[p] - pre[p-1]);
    }
    if (tid >= 128 && tid < 192){
        int p = tid - 128; float s = 0.f;
        for (int ll = 0; ll < L_; ++ll){
            float dd = fabsf(his[ll] - pre[p]);
            s += __expf(1.0f / (dd + 1e-8f));
        }
        den_s[p] = s;
    }
    const float pre0 = pre[0];
    __syncthreads();
    float dtv0[4];
    #pragma unroll
    for (int rg = 0; rg < 4; ++rg)
        dtv0[rg] = pre0 - hisq[hi16*4 + rg];
    for (int idx = tid; idx < M_*P_; idx += NT_){
        int r = idx >> 6, p = idx & 63;
        float dd = fabsf(hisq[r] - pre[p]);
        wLP[r][p] = __expf(1.0f / (dd + 1e-8f)) / den_s[p];
    }
    // wLP first read after step-0 stage barriers -> ordered.

    // ==== main scan: 64 RK4 steps ====
    for (int p = 0; p < P_; ++p){
        const float dts = dstep[p];
        float dtv[4];
        #pragma unroll
        for (int rg = 0; rg < 4; ++rg)
            dtv[rg] = (p == 0) ? dtv0[rg] : dts;
        #pragma unroll
        for (int s = 0; s < 4; ++s){
            const float c_s = (s == 2) ? 1.0f : 0.5f;
            const float w_s = (s == 0 || s == 3) ? 1.0f : 2.0f;
            __syncthreads();                                    // S_A ready
            // --- matmul1: H = S_A @ W1 (bias folded into acc init) ---
            f32x4 acc[2][2];
            #pragma unroll
            for (int nt = 0; nt < 2; ++nt){
                acc[nt][0] = f32x4{b1v[nt], b1v[nt], b1v[nt], b1v[nt]};
                acc[nt][1] = f32x4{0,0,0,0};
            }
            __builtin_amdgcn_s_setprio(1);
            #pragma unroll
            for (int kt = 0; kt < 4; ++kt){
                f16x8 a = *(const f16x8*)((const char*)sA + rdoff[kt]);
                const int hf = kt >> 1;
                acc[0][hf] = mfma16(a, w1f[kt][0], acc[0][hf]);
                acc[1][hf] = mfma16(a, w1f[kt][1], acc[1][hf]);
            }
            __builtin_amdgcn_s_setprio(0);
            // --- tanh -> S_B (paired store) ---
            #pragma unroll
            for (int rg = 0; rg < 4; ++rg){
                float t0 = tanh_fast(acc[0][0][rg] + acc[0][1][rg]);
                float t1 = tanh_fast(acc[1][0][rg] + acc[1][1][rg]);
                *stB32[rg] = pk16(t0, t1);
            }
            __syncthreads();                                    // S_B ready
            // --- matmul2: K = tanh(...) @ W2 ---
            f32x4 acd[2][2];
            #pragma unroll
            for (int nt = 0; nt < 2; ++nt){
                acd[nt][0] = f32x4{b2v[nt], b2v[nt], b2v[nt], b2v[nt]};
                acd[nt][1] = f32x4{0,0,0,0};
            }
            __builtin_amdgcn_s_setprio(1);
            #pragma unroll
            for (int kt = 0; kt < 4; ++kt){
                f16x8 a = *(const f16x8*)((const char*)sB + rdoff[kt]);
                const int hf = kt >> 1;
                acd[0][hf] = mfma16(a, w2f[kt][0], acd[0][hf]);
                acd[1][hf] = mfma16(a, w2f[kt][1], acd[1][hf]);
            }
            __builtin_amdgcn_s_setprio(0);
            // --- k_i, RK4 accumulate, next stage input (paired store) ---
            if (s < 3){
                float cdt[4];
                #pragma unroll
                for (int rg = 0; rg < 4; ++rg) cdt[rg] = c_s * dtv[rg];
                #pragma unroll
                for (int rg = 0; rg < 4; ++rg){
                    float kv0 = acd[0][0][rg] + acd[0][1][rg];
                    float kv1 = acd[1][0][rg] + acd[1][1][rg];
                    kacc[0][rg] += w_s * kv0;
                    kacc[1][rg] += w_s * kv1;
                    float s0 = __builtin_fmaf(cdt[rg], kv0, z[0][rg]);
                    float s1 = __builtin_fmaf(cdt[rg], kv1, z[1][rg]);
                    *stA32[rg] = pk16(s0, s1);
                }
            } else {
                #pragma unroll
                for (int rg = 0; rg < 4; ++rg){
                    kacc[0][rg] += acd[0][0][rg] + acd[0][1][rg];
                    kacc[1][rg] += acd[1][0][rg] + acd[1][1][rg];
                }
            }
        }
        // ---- zn update, next k1 input, weighted reduce, output ----
        float po[2] = {0.f, 0.f};
        #pragma unroll
        for (int rg = 0; rg < 4; ++rg){
            const int row = hi16*4 + rg;
            const float d6 = dtv[rg] * (1.0f/6.0f);
            float zn0 = __builtin_fmaf(d6, kacc[0][rg], z[0][rg]);
            float zn1 = __builtin_fmaf(d6, kacc[1][rg], z[1][rg]);
            z[0][rg] = zn0; z[1][rg] = zn1;
            kacc[0][rg] = 0.f; kacc[1][rg] = 0.f;
            *stA32[rg] = pk16(zn0, zn1);
            float wv = wLP[row][p];
            po[0] = __builtin_fmaf(wv, zn0, po[0]);
            po[1] = __builtin_fmaf(wv, zn1, po[1]);
        }
        #pragma unroll
        for (int nt = 0; nt < 2; ++nt){
            po[nt] += __shfl_xor(po[nt], 16);
            po[nt] += __shfl_xor(po[nt], 32);   // sum over all 16 rows
        }
        if (hi16 == 0){
            #pragma unroll
            for (int nt = 0; nt < 2; ++nt){
                const int c = nq*32 + nt*16 + r15;
                if (ATOMIC)
                    atomicAdd(&dst[((size_t)b*P_ + p)*E_ + c], po[nt]);
                else
                    dst[(((size_t)qb*B_ + b)*P_ + p)*E_ + c] = po[nt];
            }
        }
    }
}

__global__ void reduce_q(const float* __restrict__ part, float* __restrict__ out){
    const int n = B_*P_*E_;
    int i = blockIdx.x * blockDim.x + threadIdx.x;
    if (i < n){
        float s0 = part[i]       + part[i + n];
        float s1 = part[i + 2*n] + part[i + 3*n];
        float s2 = part[i + 4*n] + part[i + 5*n];
        float s3 = part[i + 6*n] + part[i + 7*n];
        out[i] = (s0 + s1) + (s2 + s3);
    }
}

extern "C" void kernel_launch(void* const* d_in, const int* in_sizes, int n_in,
                              void* d_out, int out_size, void* d_ws, size_t ws_size,
                              hipStream_t stream) {
    const float* x   = (const float*)d_in[0];
    const float* his = (const float*)d_in[1];
    const float* pre = (const float*)d_in[2];
    const float* W1  = (const float*)d_in[3];
    const float* b1  = (const float*)d_in[4];
    const float* W2  = (const float*)d_in[5];
    const float* b2  = (const float*)d_in[6];
    float* out = (float*)d_out;

    const size_t need = (size_t)8 * B_ * P_ * E_ * sizeof(float);  // 16 MB partials
    if (ws_size >= need){
        float* part = (float*)d_ws;
        wode_main<false><<<B_*8, NT_, 0, stream>>>(x, his, pre, W1, b1, W2, b2, part);
        const int n = B_*P_*E_;
        reduce_q<<<(n + 255)/256, 256, 0, stream>>>(part, out);
    } else {
        (void)hipMemsetAsync(d_out, 0, (size_t)B_*P_*E_*sizeof(float), stream);
        wode_main<true><<<B_*8, NT_, 0, stream>>>(x, his, pre, W1, b1, W2, b2, out);
    }
}